// Round 3
// baseline (7656.181 us; speedup 1.0000x reference)
//
#include <hip/hip_runtime.h>

#define TPB 256  // 4 waves; wave w = role w; 64 rows per block

static constexpr int SZ0 = 64 * 128 * 9;    // 73728
static constexpr int SZ1 = 128 * 128 * 9;   // 147456
static constexpr int SZ4 = 128 * 9;         // 1152
static constexpr int OFF0 = 0;
static constexpr int OFF1 = OFF0 + SZ0;
static constexpr int OFF2 = OFF1 + SZ1;
static constexpr int OFF3 = OFF2 + SZ1;
static constexpr int OFF4 = OFF3 + SZ1;

// ---------- helpers ----------
__device__ __forceinline__ float fast_tanh2(float x) {  // 2*tanh(x)
  float e = __expf(2.0f * x);
  return fmaf(-4.0f, __builtin_amdgcn_rcpf(e + 1.0f), 2.0f);
}
__device__ __forceinline__ float gelu_exact(float v) {
  return 0.5f * v * (1.0f + erff(v * 0.70710678f));
}

// ---------- weight fusion: layout [p][n][q] ----------
__global__ void fuse_w(const float* __restrict__ W, const float* __restrict__ tW,
                       float* __restrict__ out, int P, int Q, int total) {
  int i = blockIdx.x * 256 + threadIdx.x;
  if (i >= total) return;
  int q = i % Q;
  int r = i / Q;
  int n = r % 9;
  int p = r / 9;
  out[i] = tW[(q * P + p) * 9 + n] * W[q * P + p];
}

// ---------- per-layer qc loop ----------
// Each thread accumulates its p-quarter (NP channels, m in regs) for every qc,
// partials exchanged through xb; owner adds residual and commits to hL.
template <int NP, bool RES>
__device__ __forceinline__ void kan_qc(const float* __restrict__ wbase,  // role-offset, wave-uniform
                                       const float (&m)[32],
                                       float* __restrict__ hL, float* __restrict__ xb,
                                       int lane, int role) {
#pragma unroll 1
  for (int qc = 0; qc < 16; ++qc) {
    float acc[8];
#pragma unroll
    for (int j = 0; j < 8; ++j) acc[j] = 0.0f;
    const float* wq = wbase + qc * 8;
#pragma unroll
    for (int pp = 0; pp < NP; ++pp) {
      float mm = m[pp];
      const float* w = wq + pp * 9 * 128;
      // n = 0 (U0 = 1), n = 1 (U1 = m)
#pragma unroll
      for (int j = 0; j < 8; ++j) acc[j] += w[j];
#pragma unroll
      for (int j = 0; j < 8; ++j) acc[j] = fmaf(mm, w[128 + j], acc[j]);
      float um2 = 1.0f, um1 = mm;
#pragma unroll
      for (int n = 2; n < 9; ++n) {
        float u = fmaf(mm, um1, -um2);
        um2 = um1;
        um1 = u;
        const float* wn = w + n * 128;
#pragma unroll
        for (int j = 0; j < 8; ++j) acc[j] = fmaf(u, wn[j], acc[j]);
      }
    }
    int own = qc >> 2;
    if (role != own) {
      int slot = role - (role > own ? 1 : 0);
#pragma unroll
      for (int j = 0; j < 8; ++j) xb[lane * 25 + slot * 8 + j] = acc[j];
    }
    __syncthreads();
    if (role == own) {
#pragma unroll
      for (int j = 0; j < 8; ++j) {
        float v = acc[j] + xb[lane * 25 + j] + xb[lane * 25 + 8 + j] + xb[lane * 25 + 16 + j];
        int ch = qc * 8 + j;
        if (RES) v += hL[lane * 129 + ch];
        hL[lane * 129 + ch] = v;
      }
    }
    __syncthreads();
  }
}

__device__ __forceinline__ void load_tanh(float (&m)[32], const float* __restrict__ hL,
                                          int lane, int role) {
#pragma unroll
  for (int i = 0; i < 32; ++i) m[i] = fast_tanh2(hL[lane * 129 + role * 32 + i]);
}

// ---------- main fused kernel ----------
__global__ void __launch_bounds__(TPB, 4)
kan_main(const float* __restrict__ x, const float* __restrict__ Bm,
         const float* __restrict__ wf, float* __restrict__ out) {
  __shared__ float hL[64 * 129];  // residual stream, padded (33 KB)
  __shared__ float xb[64 * 25];   // partial-sum exchange, padded (6.4 KB)
  int tid = threadIdx.x;
  int lane = tid & 63;
  int role = tid >> 6;
  int urole = __builtin_amdgcn_readfirstlane(role);
  int row_g = blockIdx.x * 64 + lane;

  float m[32];

  // Fourier features -> m for layer0 input (this thread's 16 channels)
  {
    const float4* xp = (const float4*)(x + (size_t)row_g * 8);
    float4 a = xp[0], c = xp[1];
    float xv[8] = {a.x, a.y, a.z, a.w, c.x, c.y, c.z, c.w};
    const float* Bb = Bm + (urole & 1) * 16;  // proj column offset (wave-uniform)
    bool do_sin = (urole < 2);
#pragma unroll
    for (int j = 0; j < 16; ++j) {
      float r = 0.0f;
#pragma unroll
      for (int k = 0; k < 8; ++k) r = fmaf(xv[k], Bb[k * 32 + j], r);
      float ang = 6.2831855f * r;
      float s, cc;
      sincosf(ang, &s, &cc);
      m[j] = fast_tanh2(do_sin ? s : cc);
    }
  }

  // L0: P=64 (16 p/role), Q=128, no residual
  kan_qc<16, false>(wf + OFF0 + urole * (16 * 9 * 128), m, hL, xb, lane, role);

  // L1..L3: P=128 (32 p/role), residual
#pragma unroll 1
  for (int l = 0; l < 3; ++l) {
    load_tanh(m, hL, lane, role);
    kan_qc<32, true>(wf + OFF1 + l * SZ1 + urole * (32 * 9 * 128), m, hL, xb, lane, role);
  }

  // L4: 128 -> 1
  load_tanh(m, hL, lane, role);
  float part = 0.0f;
  {
    const float* w4 = wf + OFF4 + urole * 32 * 9;
#pragma unroll
    for (int pp = 0; pp < 32; ++pp) {
      float mm = m[pp];
      const float* w = w4 + pp * 9;
      part += w[0];
      part = fmaf(mm, w[1], part);
      float um2 = 1.0f, um1 = mm;
#pragma unroll
      for (int n = 2; n < 9; ++n) {
        float u = fmaf(mm, um1, -um2);
        um2 = um1;
        um1 = u;
        part = fmaf(u, w[n], part);
      }
    }
  }
  if (role != 0) xb[lane * 25 + (role - 1)] = part;
  __syncthreads();
  if (role == 0) {
    float v = part + xb[lane * 25] + xb[lane * 25 + 1] + xb[lane * 25 + 2];
    // cheby-gelu, degree 5, T1 = tanh(v)
    float t = 0.5f * fast_tanh2(v);
    float m2 = t + t;
    float tm2 = 1.0f, tm1 = t;
    float y = gelu_exact(1.0f) + gelu_exact(t);
#pragma unroll
    for (int n = 2; n <= 5; ++n) {
      float tn = fmaf(m2, tm1, -tm2);
      tm2 = tm1;
      tm1 = tn;
      y += gelu_exact(tn);
    }
    out[row_g] = y;
  }
}

extern "C" void kernel_launch(void* const* d_in, const int* in_sizes, int n_in,
                              void* d_out, int out_size, void* d_ws, size_t ws_size,
                              hipStream_t stream) {
  const float* x   = (const float*)d_in[0];
  const float* Bm  = (const float*)d_in[1];
  const float* W0  = (const float*)d_in[2];
  const float* tW0 = (const float*)d_in[3];
  const float* W1  = (const float*)d_in[4];
  const float* tW1 = (const float*)d_in[5];
  const float* W2  = (const float*)d_in[6];
  const float* tW2 = (const float*)d_in[7];
  const float* W3  = (const float*)d_in[8];
  const float* tW3 = (const float*)d_in[9];
  const float* W4  = (const float*)d_in[10];
  const float* tW4 = (const float*)d_in[11];
  float* wf = (float*)d_ws;

  fuse_w<<<(SZ0 + 255) / 256, 256, 0, stream>>>(W0, tW0, wf + OFF0, 64, 128, SZ0);
  fuse_w<<<(SZ1 + 255) / 256, 256, 0, stream>>>(W1, tW1, wf + OFF1, 128, 128, SZ1);
  fuse_w<<<(SZ1 + 255) / 256, 256, 0, stream>>>(W2, tW2, wf + OFF2, 128, 128, SZ1);
  fuse_w<<<(SZ1 + 255) / 256, 256, 0, stream>>>(W3, tW3, wf + OFF3, 128, 128, SZ1);
  fuse_w<<<(SZ4 + 255) / 256, 256, 0, stream>>>(W4, tW4, wf + OFF4, 128, 1, SZ4);

  kan_main<<<131072 / 64, TPB, 0, stream>>>(x, Bm, wf, (float*)d_out);
}

// Round 6
// 498.842 us; speedup vs baseline: 15.3479x; 15.3479x over previous
//
#include <hip/hip_runtime.h>

#define TPB 256  // 4 independent waves per block; wave = 32 rows

typedef _Float16 f16x8 __attribute__((ext_vector_type(8)));
typedef float f32x4 __attribute__((ext_vector_type(4)));

// fp16 weight tiles (B-fragment order), element offsets within each plane:
static constexpr int WT_L0 = 0;        // 8n*2s*8t*512 = 65536
static constexpr int WT_L1 = 65536;    // 8n*4s*8t*512 = 131072 each
static constexpr int WT_L2 = 196608;
static constexpr int WT_L3 = 327680;
static constexpr int WT_END = 458752;          // fp16 elements per plane (hi, lo)
static constexpr int F32_BASE = WT_END;        // float index into ws (2 planes = WT_END floats)
// float region: bias[4][128] then w4[1152]
static constexpr int MST = 132;                // mlds row stride (floats)
static constexpr float LO_SCALE = 2048.0f;     // 2^11
static constexpr float LO_INV = 1.0f / 2048.0f;

// ---------- helpers ----------
__device__ __forceinline__ float fast_tanh2(float x) {  // 2*tanh(x)
  float e = __expf(2.0f * x);
  return fmaf(-4.0f, __builtin_amdgcn_rcpf(e + 1.0f), 2.0f);
}
__device__ __forceinline__ float gelu_exact(float v) {
  return 0.5f * v * (1.0f + erff(v * 0.70710678f));
}

// ---------- fusion kernels ----------
// fp16 tiles: tile(n-1, s, t); within-tile element e = lane*8 + j:
//   B col q = lane&15 -> bits 3..6; k-group g = lane>>4 -> bits 7..8
// e = g*128 + q*8 + j; p = s*32 + g*8 + j; qg = t*16 + q; coef n = n1+1
// Writes hi plane and scaled-residual lo plane.
__global__ void fuse_w_f16(const float* __restrict__ W, const float* __restrict__ tW,
                           _Float16* __restrict__ out_hi, _Float16* __restrict__ out_lo,
                           int P, int total, int sbits) {
  int i = blockIdx.x * 256 + threadIdx.x;
  if (i >= total) return;
  int j = i & 7, q = (i >> 3) & 15, g = (i >> 7) & 3, t = (i >> 9) & 7;
  int s = (i >> 12) & ((1 << sbits) - 1);
  int n1 = i >> (12 + sbits);  // n-1 in 0..7
  int p = s * 32 + g * 8 + j;
  int qg = t * 16 + q;
  float v = tW[(qg * P + p) * 9 + (n1 + 1)] * W[qg * P + p];
  _Float16 hi = (_Float16)v;
  out_hi[i] = hi;
  out_lo[i] = (_Float16)((v - (float)hi) * LO_SCALE);
}
// bias[q] = sum_p tW[q,p,0]*W[q,p]   (the n=0 / T0=1 term)
__global__ void fuse_bias(const float* __restrict__ W, const float* __restrict__ tW,
                          float* __restrict__ bias, int P, int Q) {
  int q = blockIdx.x * 64 + threadIdx.x;
  if (q >= Q) return;
  float s = 0.0f;
  for (int p = 0; p < P; ++p) s += tW[(q * P + p) * 9] * W[q * P + p];
  bias[q] = s;
}
// w4[p*9+n] = tW4[p*9+n] * W4[p]  (fp32, Q=1)
__global__ void fuse_w4(const float* __restrict__ W, const float* __restrict__ tW,
                        float* __restrict__ out) {
  int i = blockIdx.x * 128 + threadIdx.x;
  if (i >= 1152) return;
  out[i] = tW[i] * W[i / 9];
}

// ---------- per-layer MFMA with hi/lo split-precision ----------
// mlds holds m=2tanh(h_in) as fp32 [32 rows][MST], p in [0, S*32)
// acc frags: value(row = mt*16 + (l>>4)*4 + j, q = qt*16 + (l&15))
template <int S, bool RES>
__device__ __forceinline__ void layer_mfma(const float* __restrict__ mlds,
                                           const _Float16* __restrict__ wt_hi,
                                           const _Float16* __restrict__ wt_lo,
                                           const float* __restrict__ bias,
                                           f32x4 (&acc)[2][8], int l) {
  f32x4 accc[2][8];  // correction accumulator, scaled by 2^11
  // init: acc = (RES ? acc : 0) + bias[q]; accc = 0
#pragma unroll
  for (int qt = 0; qt < 8; ++qt) {
    float bv = bias[qt * 16 + (l & 15)];
#pragma unroll
    for (int mt = 0; mt < 2; ++mt)
#pragma unroll
      for (int j = 0; j < 4; ++j) {
        if (RES) acc[mt][qt][j] += bv; else acc[mt][qt][j] = bv;
        accc[mt][qt][j] = 0.0f;
      }
  }
  const _Float16* wl_hi = wt_hi + (size_t)l * 8;  // lane's 16B slot per 1KB tile
  const _Float16* wl_lo = wt_lo + (size_t)l * 8;
#pragma unroll 1
  for (int s = 0; s < S; ++s) {
    // A-side m: lane needs rows mt*16+(l&15), p = s*32 + (l>>4)*8 + i
    float mv[2][8], up[2][8], uc[2][8];
#pragma unroll
    for (int mt = 0; mt < 2; ++mt) {
      const f32x4* mp =
          (const f32x4*)(mlds + (mt * 16 + (l & 15)) * MST + s * 32 + ((l >> 4) * 8));
      f32x4 lo = mp[0], hi = mp[1];
#pragma unroll
      for (int i = 0; i < 4; ++i) { mv[mt][i] = lo[i]; mv[mt][4 + i] = hi[i]; }
#pragma unroll
      for (int i = 0; i < 8; ++i) { up[mt][i] = 1.0f; uc[mt][i] = mv[mt][i]; }
    }
#pragma unroll 1
    for (int n = 1; n <= 8; ++n) {
      const size_t toff = (size_t)((n - 1) * S + s) * 8 * 512;
      const _Float16* wn_hi = wl_hi + toff;
      const _Float16* wn_lo = wl_lo + toff;
      // pack current T_n to hi/lo fp16 A-frags
      f16x8 af_hi[2], af_lo[2];
#pragma unroll
      for (int mt = 0; mt < 2; ++mt)
#pragma unroll
        for (int i = 0; i < 8; ++i) {
          float v = uc[mt][i];
          _Float16 h = (_Float16)v;
          af_hi[mt][i] = h;
          af_lo[mt][i] = (_Float16)((v - (float)h) * LO_SCALE);
        }
      // advance recurrence: T_{n+1} = m*T_n - T_{n-1}
#pragma unroll
      for (int mt = 0; mt < 2; ++mt)
#pragma unroll
        for (int i = 0; i < 8; ++i) {
          float u = fmaf(mv[mt][i], uc[mt][i], -up[mt][i]);
          up[mt][i] = uc[mt][i];
          uc[mt][i] = u;
        }
#pragma unroll
      for (int t = 0; t < 8; ++t) {
        f16x8 bh = *(const f16x8*)(wn_hi + t * 512);
        f16x8 bl = *(const f16x8*)(wn_lo + t * 512);
        acc[0][t] = __builtin_amdgcn_mfma_f32_16x16x32_f16(af_hi[0], bh, acc[0][t], 0, 0, 0);
        acc[1][t] = __builtin_amdgcn_mfma_f32_16x16x32_f16(af_hi[1], bh, acc[1][t], 0, 0, 0);
        accc[0][t] = __builtin_amdgcn_mfma_f32_16x16x32_f16(af_lo[0], bh, accc[0][t], 0, 0, 0);
        accc[1][t] = __builtin_amdgcn_mfma_f32_16x16x32_f16(af_lo[1], bh, accc[1][t], 0, 0, 0);
        accc[0][t] = __builtin_amdgcn_mfma_f32_16x16x32_f16(af_hi[0], bl, accc[0][t], 0, 0, 0);
        accc[1][t] = __builtin_amdgcn_mfma_f32_16x16x32_f16(af_hi[1], bl, accc[1][t], 0, 0, 0);
      }
    }
  }
  // fold correction: acc += accc * 2^-11
#pragma unroll
  for (int mt = 0; mt < 2; ++mt)
#pragma unroll
    for (int t = 0; t < 8; ++t)
#pragma unroll
      for (int j = 0; j < 4; ++j)
        acc[mt][t][j] = fmaf(accc[mt][t][j], LO_INV, acc[mt][t][j]);
}

// write m = 2tanh(acc) into mlds[row][q] from C-layout frags
__device__ __forceinline__ void write_m(float* __restrict__ mlds,
                                        const f32x4 (&acc)[2][8], int l) {
#pragma unroll
  for (int mt = 0; mt < 2; ++mt)
#pragma unroll
    for (int qt = 0; qt < 8; ++qt)
#pragma unroll
      for (int j = 0; j < 4; ++j) {
        int row = mt * 16 + ((l >> 4) * 4 + j);
        mlds[row * MST + qt * 16 + (l & 15)] = fast_tanh2(acc[mt][qt][j]);
      }
}

// ---------- main kernel: zero barriers, waves independent ----------
__global__ void __launch_bounds__(TPB, 2)
kan_mfma(const float* __restrict__ x, const float* __restrict__ Bm,
         const _Float16* __restrict__ wt_hi, const _Float16* __restrict__ wt_lo,
         const float* __restrict__ bias, const float* __restrict__ w4,
         float* __restrict__ out) {
  __shared__ float mlds_all[4][32 * MST];
  int tid = threadIdx.x;
  int l = tid & 63;
  int w = tid >> 6;
  float* mlds = mlds_all[w];
  int row0 = blockIdx.x * 128 + w * 32;

  // ---- Fourier features -> m for L0 ----
  {
    int r = l & 31, hh = l >> 5;
    const float4* xp = (const float4*)(x + (size_t)(row0 + r) * 8);
    float4 a = xp[0], c4 = xp[1];
    float xv[8] = {a.x, a.y, a.z, a.w, c4.x, c4.y, c4.z, c4.w};
#pragma unroll
    for (int jj = 0; jj < 16; ++jj) {
      int j = hh * 16 + jj;
      float pr = 0.0f;
#pragma unroll
      for (int k = 0; k < 8; ++k) pr = fmaf(xv[k], Bm[k * 32 + j], pr);
      float ang = 6.2831853071795864f * pr;
      float sv, cv;
      sincosf(ang, &sv, &cv);
      mlds[r * MST + j] = fast_tanh2(sv);
      mlds[r * MST + 32 + j] = fast_tanh2(cv);
    }
  }

  f32x4 acc[2][8];
  layer_mfma<2, false>(mlds, wt_hi + WT_L0, wt_lo + WT_L0, bias + 0, acc, l);
  write_m(mlds, acc, l);
  layer_mfma<4, true>(mlds, wt_hi + WT_L1, wt_lo + WT_L1, bias + 128, acc, l);
  write_m(mlds, acc, l);
  layer_mfma<4, true>(mlds, wt_hi + WT_L2, wt_lo + WT_L2, bias + 256, acc, l);
  write_m(mlds, acc, l);
  layer_mfma<4, true>(mlds, wt_hi + WT_L3, wt_lo + WT_L3, bias + 384, acc, l);
  write_m(mlds, acc, l);

  // ---- L4: 128 -> 1 (fp32 scalar, split p-halves across lane pairs) ----
  {
    int r = l & 31, ph = l >> 5;
    const float* mrow = mlds + r * MST + ph * 64;
    const float* w4h = w4 + ph * 64 * 9;
    float part = 0.0f;
#pragma unroll 4
    for (int p = 0; p < 64; ++p) {
      float mm = mrow[p];
      const float* wp = w4h + p * 9;
      part += wp[0];
      part = fmaf(mm, wp[1], part);
      float u2 = 1.0f, u1 = mm;
#pragma unroll
      for (int n = 2; n < 9; ++n) {
        float u = fmaf(mm, u1, -u2);
        u2 = u1;
        u1 = u;
        part = fmaf(u, wp[n], part);
      }
    }
    part += __shfl_xor(part, 32);
    if (l < 32) {
      float v = part;
      // cheby-gelu, degree 5, T1 = tanh(v)
      float t = 0.5f * fast_tanh2(v);
      float m2 = t + t;
      float tm2 = 1.0f, tm1 = t;
      float y = gelu_exact(1.0f) + gelu_exact(t);
#pragma unroll
      for (int n = 2; n <= 5; ++n) {
        float tn = fmaf(m2, tm1, -tm2);
        tm2 = tm1;
        tm1 = tn;
        y += gelu_exact(tn);
      }
      out[row0 + r] = y;
    }
  }
}

extern "C" void kernel_launch(void* const* d_in, const int* in_sizes, int n_in,
                              void* d_out, int out_size, void* d_ws, size_t ws_size,
                              hipStream_t stream) {
  const float* x   = (const float*)d_in[0];
  const float* Bm  = (const float*)d_in[1];
  const float* W0  = (const float*)d_in[2];
  const float* tW0 = (const float*)d_in[3];
  const float* W1  = (const float*)d_in[4];
  const float* tW1 = (const float*)d_in[5];
  const float* W2  = (const float*)d_in[6];
  const float* tW2 = (const float*)d_in[7];
  const float* W3  = (const float*)d_in[8];
  const float* tW3 = (const float*)d_in[9];
  const float* W4  = (const float*)d_in[10];
  const float* tW4 = (const float*)d_in[11];

  _Float16* wt_hi = (_Float16*)d_ws;
  _Float16* wt_lo = wt_hi + WT_END;
  float* fws = (float*)d_ws + F32_BASE;
  float* bias = fws;        // 4*128 floats
  float* w4 = fws + 512;    // 1152 floats

  fuse_w_f16<<<65536 / 256, 256, 0, stream>>>(W0, tW0, wt_hi + WT_L0, wt_lo + WT_L0, 64, 65536, 1);
  fuse_w_f16<<<131072 / 256, 256, 0, stream>>>(W1, tW1, wt_hi + WT_L1, wt_lo + WT_L1, 128, 131072, 2);
  fuse_w_f16<<<131072 / 256, 256, 0, stream>>>(W2, tW2, wt_hi + WT_L2, wt_lo + WT_L2, 128, 131072, 2);
  fuse_w_f16<<<131072 / 256, 256, 0, stream>>>(W3, tW3, wt_hi + WT_L3, wt_lo + WT_L3, 128, 131072, 2);
  fuse_bias<<<2, 64, 0, stream>>>(W0, tW0, bias + 0, 64, 128);
  fuse_bias<<<2, 64, 0, stream>>>(W1, tW1, bias + 128, 128, 128);
  fuse_bias<<<2, 64, 0, stream>>>(W2, tW2, bias + 256, 128, 128);
  fuse_bias<<<2, 64, 0, stream>>>(W3, tW3, bias + 384, 128, 128);
  fuse_w4<<<9, 128, 0, stream>>>(W4, tW4, w4);

  kan_mfma<<<131072 / 128, TPB, 0, stream>>>(x, Bm, wt_hi, wt_lo, bias, w4, (float*)d_out);
}

// Round 8
// 388.137 us; speedup vs baseline: 19.7255x; 1.2852x over previous
//
#include <hip/hip_runtime.h>

#define TPB 256  // 4 independent waves per block; wave = 32 rows

typedef _Float16 f16x8 __attribute__((ext_vector_type(8)));
typedef __fp16 h16x2 __attribute__((ext_vector_type(2)));  // cvt_pkrtz native type
typedef float f32x4 __attribute__((ext_vector_type(4)));

// fp16 weight tiles (B-fragment order), element offsets within each plane:
static constexpr int WT_L0 = 0;        // 8n*2s*8t*512 = 65536
static constexpr int WT_L1 = 65536;    // 8n*4s*8t*512 = 131072 each
static constexpr int WT_L2 = 196608;
static constexpr int WT_L3 = 327680;
static constexpr int WT_END = 458752;          // fp16 elements per plane (hi, lo)
static constexpr int F32_BASE = WT_END;        // float index into ws (2 f16 planes = WT_END floats)
// float region: bias[4][128] then w4[1152]
static constexpr int MST = 132;                // mlds row stride (floats)

// ---------- helpers ----------
__device__ __forceinline__ float fast_tanh2(float x) {  // 2*tanh(x)
  float e = __expf(2.0f * x);
  return fmaf(-4.0f, __builtin_amdgcn_rcpf(e + 1.0f), 2.0f);
}
__device__ __forceinline__ float gelu_exact(float v) {
  return 0.5f * v * (1.0f + erff(v * 0.70710678f));
}

// ---------- fusion kernels ----------
// fp16 tiles: tile(n-1, s, t); within-tile element e = lane*8 + j:
//   B col q = lane&15 -> bits 3..6; k-group g = lane>>4 -> bits 7..8
// e = g*128 + q*8 + j; p = s*32 + g*8 + j; qg = t*16 + q; coef n = n1+1
// lo plane is the UNSCALED fp16 residual (tiny-abs terms; fp16 denorms ok).
__global__ void fuse_w_f16(const float* __restrict__ W, const float* __restrict__ tW,
                           _Float16* __restrict__ out_hi, _Float16* __restrict__ out_lo,
                           int P, int total, int sbits) {
  int i = blockIdx.x * 256 + threadIdx.x;
  if (i >= total) return;
  int j = i & 7, q = (i >> 3) & 15, g = (i >> 7) & 3, t = (i >> 9) & 7;
  int s = (i >> 12) & ((1 << sbits) - 1);
  int n1 = i >> (12 + sbits);  // n-1 in 0..7
  int p = s * 32 + g * 8 + j;
  int qg = t * 16 + q;
  float v = tW[(qg * P + p) * 9 + (n1 + 1)] * W[qg * P + p];
  _Float16 hi = (_Float16)v;
  out_hi[i] = hi;
  out_lo[i] = (_Float16)(v - (float)hi);
}
// bias[q] = sum_p tW[q,p,0]*W[q,p]   (the n=0 / T0=1 term)
__global__ void fuse_bias(const float* __restrict__ W, const float* __restrict__ tW,
                          float* __restrict__ bias, int P, int Q) {
  int q = blockIdx.x * 64 + threadIdx.x;
  if (q >= Q) return;
  float s = 0.0f;
  for (int p = 0; p < P; ++p) s += tW[(q * P + p) * 9] * W[q * P + p];
  bias[q] = s;
}
// w4[p*9+n] = tW4[p*9+n] * W4[p]  (fp32, Q=1)
__global__ void fuse_w4(const float* __restrict__ W, const float* __restrict__ tW,
                        float* __restrict__ out) {
  int i = blockIdx.x * 128 + threadIdx.x;
  if (i >= 1152) return;
  out[i] = tW[i] * W[i / 9];
}

// ---------- per-layer MFMA, split-precision, single accumulator ----------
// mlds holds m=2tanh(h_in) as fp32 [32 rows][MST], p in [0, S*32)
// acc frags: value(row = mt*16 + (l>>4)*4 + j, q = qt*16 + (l&15))
template <int S, bool RES>
__device__ __forceinline__ void layer_mfma(const float* __restrict__ mlds,
                                           const _Float16* __restrict__ wt_hi,
                                           const _Float16* __restrict__ wt_lo,
                                           const float* __restrict__ bias,
                                           f32x4 (&acc)[2][8], int l) {
  // init: acc = (RES ? acc : 0) + bias[q]
#pragma unroll
  for (int qt = 0; qt < 8; ++qt) {
    float bv = bias[qt * 16 + (l & 15)];
#pragma unroll
    for (int mt = 0; mt < 2; ++mt)
#pragma unroll
      for (int j = 0; j < 4; ++j) {
        if (RES) acc[mt][qt][j] += bv; else acc[mt][qt][j] = bv;
      }
  }
  const _Float16* wl_hi = wt_hi + (size_t)l * 8;  // lane's 16B slot per 1KB tile
  const _Float16* wl_lo = wt_lo + (size_t)l * 8;
#pragma unroll 1
  for (int s = 0; s < S; ++s) {
    // A-side m: lane needs rows mt*16+(l&15), p = s*32 + (l>>4)*8 + i
    float mv[2][8], up[2][8], uc[2][8];
#pragma unroll
    for (int mt = 0; mt < 2; ++mt) {
      const f32x4* mp =
          (const f32x4*)(mlds + (mt * 16 + (l & 15)) * MST + s * 32 + ((l >> 4) * 8));
      f32x4 lo = mp[0], hi = mp[1];
#pragma unroll
      for (int i = 0; i < 4; ++i) { mv[mt][i] = lo[i]; mv[mt][4 + i] = hi[i]; }
#pragma unroll
      for (int i = 0; i < 8; ++i) { up[mt][i] = 1.0f; uc[mt][i] = mv[mt][i]; }
    }
#pragma unroll 1
    for (int n = 1; n <= 8; ++n) {
      const size_t toff = (size_t)((n - 1) * S + s) * 8 * 512;
      const _Float16* wn_hi = wl_hi + toff;
      const _Float16* wn_lo = wl_lo + toff;
      // hoisted B-fragment loads (issued before pack; pack+recurrence covers latency)
      f16x8 bh[8], bl[8];
#pragma unroll
      for (int t = 0; t < 8; ++t) bh[t] = *(const f16x8*)(wn_hi + t * 512);
#pragma unroll
      for (int t = 0; t < 8; ++t) bl[t] = *(const f16x8*)(wn_lo + t * 512);
      // pack current T_n to hi (RTZ) + unscaled-lo fp16 A-frags via cvt_pkrtz
      f16x8 af_hi[2], af_lo[2];
#pragma unroll
      for (int mt = 0; mt < 2; ++mt) {
        union U8 { h16x2 h2[4]; f16x8 v; } uh, ul;
#pragma unroll
        for (int i = 0; i < 4; ++i) {
          float v0 = uc[mt][2 * i], v1 = uc[mt][2 * i + 1];
          h16x2 h = __builtin_amdgcn_cvt_pkrtz(v0, v1);
          float l0 = v0 - (float)h[0];
          float l1 = v1 - (float)h[1];
          uh.h2[i] = h;
          ul.h2[i] = __builtin_amdgcn_cvt_pkrtz(l0, l1);
        }
        af_hi[mt] = uh.v;
        af_lo[mt] = ul.v;
      }
      // advance recurrence: T_{n+1} = m*T_n - T_{n-1}
#pragma unroll
      for (int mt = 0; mt < 2; ++mt)
#pragma unroll
        for (int i = 0; i < 8; ++i) {
          float u = fmaf(mv[mt][i], uc[mt][i], -up[mt][i]);
          up[mt][i] = uc[mt][i];
          uc[mt][i] = u;
        }
      // 3 passes of 16 MFMAs; same-acc write distance = 16 instrs (no dep stalls)
#pragma unroll
      for (int t = 0; t < 8; ++t) {
        acc[0][t] = __builtin_amdgcn_mfma_f32_16x16x32_f16(af_hi[0], bh[t], acc[0][t], 0, 0, 0);
        acc[1][t] = __builtin_amdgcn_mfma_f32_16x16x32_f16(af_hi[1], bh[t], acc[1][t], 0, 0, 0);
      }
#pragma unroll
      for (int t = 0; t < 8; ++t) {
        acc[0][t] = __builtin_amdgcn_mfma_f32_16x16x32_f16(af_lo[0], bh[t], acc[0][t], 0, 0, 0);
        acc[1][t] = __builtin_amdgcn_mfma_f32_16x16x32_f16(af_lo[1], bh[t], acc[1][t], 0, 0, 0);
      }
#pragma unroll
      for (int t = 0; t < 8; ++t) {
        acc[0][t] = __builtin_amdgcn_mfma_f32_16x16x32_f16(af_hi[0], bl[t], acc[0][t], 0, 0, 0);
        acc[1][t] = __builtin_amdgcn_mfma_f32_16x16x32_f16(af_hi[1], bl[t], acc[1][t], 0, 0, 0);
      }
    }
  }
}

// write m = 2tanh(acc) into mlds[row][q] from C-layout frags
__device__ __forceinline__ void write_m(float* __restrict__ mlds,
                                        const f32x4 (&acc)[2][8], int l) {
#pragma unroll
  for (int mt = 0; mt < 2; ++mt)
#pragma unroll
    for (int qt = 0; qt < 8; ++qt)
#pragma unroll
      for (int j = 0; j < 4; ++j) {
        int row = mt * 16 + ((l >> 4) * 4 + j);
        mlds[row * MST + qt * 16 + (l & 15)] = fast_tanh2(acc[mt][qt][j]);
      }
}

// ---------- main kernel: zero barriers, waves independent ----------
__global__ void __launch_bounds__(TPB, 2)
kan_mfma(const float* __restrict__ x, const float* __restrict__ Bm,
         const _Float16* __restrict__ wt_hi, const _Float16* __restrict__ wt_lo,
         const float* __restrict__ bias, const float* __restrict__ w4,
         float* __restrict__ out) {
  __shared__ float mlds_all[4][32 * MST];
  int tid = threadIdx.x;
  int l = tid & 63;
  int w = tid >> 6;
  float* mlds = mlds_all[w];
  int row0 = blockIdx.x * 128 + w * 32;

  // ---- Fourier features -> m for L0 ----
  {
    int r = l & 31, hh = l >> 5;
    const float4* xp = (const float4*)(x + (size_t)(row0 + r) * 8);
    float4 a = xp[0], c4 = xp[1];
    float xv[8] = {a.x, a.y, a.z, a.w, c4.x, c4.y, c4.z, c4.w};
#pragma unroll
    for (int jj = 0; jj < 16; ++jj) {
      int j = hh * 16 + jj;
      float pr = 0.0f;
#pragma unroll
      for (int k = 0; k < 8; ++k) pr = fmaf(xv[k], Bm[k * 32 + j], pr);
      float ang = 6.2831853071795864f * pr;
      float sv, cv;
      sincosf(ang, &sv, &cv);
      mlds[r * MST + j] = fast_tanh2(sv);
      mlds[r * MST + 32 + j] = fast_tanh2(cv);
    }
  }

  f32x4 acc[2][8];
  layer_mfma<2, false>(mlds, wt_hi + WT_L0, wt_lo + WT_L0, bias + 0, acc, l);
  write_m(mlds, acc, l);
  layer_mfma<4, true>(mlds, wt_hi + WT_L1, wt_lo + WT_L1, bias + 128, acc, l);
  write_m(mlds, acc, l);
  layer_mfma<4, true>(mlds, wt_hi + WT_L2, wt_lo + WT_L2, bias + 256, acc, l);
  write_m(mlds, acc, l);
  layer_mfma<4, true>(mlds, wt_hi + WT_L3, wt_lo + WT_L3, bias + 384, acc, l);
  write_m(mlds, acc, l);

  // ---- L4: 128 -> 1 (fp32 scalar, split p-halves across lane pairs) ----
  {
    int r = l & 31, ph = l >> 5;
    const float* mrow = mlds + r * MST + ph * 64;
    const float* w4h = w4 + ph * 64 * 9;
    float part = 0.0f;
#pragma unroll 4
    for (int p = 0; p < 64; ++p) {
      float mm = mrow[p];
      const float* wp = w4h + p * 9;
      part += wp[0];
      part = fmaf(mm, wp[1], part);
      float u2 = 1.0f, u1 = mm;
#pragma unroll
      for (int n = 2; n < 9; ++n) {
        float u = fmaf(mm, u1, -u2);
        u2 = u1;
        u1 = u;
        part = fmaf(u, wp[n], part);
      }
    }
    part += __shfl_xor(part, 32);
    if (l < 32) {
      float v = part;
      // cheby-gelu, degree 5, T1 = tanh(v)
      float t = 0.5f * fast_tanh2(v);
      float m2 = t + t;
      float tm2 = 1.0f, tm1 = t;
      float y = gelu_exact(1.0f) + gelu_exact(t);
#pragma unroll
      for (int n = 2; n <= 5; ++n) {
        float tn = fmaf(m2, tm1, -tm2);
        tm2 = tm1;
        tm1 = tn;
        y += gelu_exact(tn);
      }
      out[row0 + r] = y;
    }
  }
}

extern "C" void kernel_launch(void* const* d_in, const int* in_sizes, int n_in,
                              void* d_out, int out_size, void* d_ws, size_t ws_size,
                              hipStream_t stream) {
  const float* x   = (const float*)d_in[0];
  const float* Bm  = (const float*)d_in[1];
  const float* W0  = (const float*)d_in[2];
  const float* tW0 = (const float*)d_in[3];
  const float* W1  = (const float*)d_in[4];
  const float* tW1 = (const float*)d_in[5];
  const float* W2  = (const float*)d_in[6];
  const float* tW2 = (const float*)d_in[7];
  const float* W3  = (const float*)d_in[8];
  const float* tW3 = (const float*)d_in[9];
  const float* W4  = (const float*)d_in[10];
  const float* tW4 = (const float*)d_in[11];

  _Float16* wt_hi = (_Float16*)d_ws;
  _Float16* wt_lo = wt_hi + WT_END;
  float* fws = (float*)d_ws + F32_BASE;
  float* bias = fws;        // 4*128 floats
  float* w4 = fws + 512;    // 1152 floats

  fuse_w_f16<<<65536 / 256, 256, 0, stream>>>(W0, tW0, wt_hi + WT_L0, wt_lo + WT_L0, 64, 65536, 1);
  fuse_w_f16<<<131072 / 256, 256, 0, stream>>>(W1, tW1, wt_hi + WT_L1, wt_lo + WT_L1, 128, 131072, 2);
  fuse_w_f16<<<131072 / 256, 256, 0, stream>>>(W2, tW2, wt_hi + WT_L2, wt_lo + WT_L2, 128, 131072, 2);
  fuse_w_f16<<<131072 / 256, 256, 0, stream>>>(W3, tW3, wt_hi + WT_L3, wt_lo + WT_L3, 128, 131072, 2);
  fuse_bias<<<2, 64, 0, stream>>>(W0, tW0, bias + 0, 64, 128);
  fuse_bias<<<2, 64, 0, stream>>>(W1, tW1, bias + 128, 128, 128);
  fuse_bias<<<2, 64, 0, stream>>>(W2, tW2, bias + 256, 128, 128);
  fuse_bias<<<2, 64, 0, stream>>>(W3, tW3, bias + 384, 128, 128);
  fuse_w4<<<9, 128, 0, stream>>>(W4, tW4, w4);

  kan_mfma<<<131072 / 128, TPB, 0, stream>>>(x, Bm, wt_hi, wt_lo, bias, w4, (float*)d_out);
}